// Round 3
// baseline (147.981 us; speedup 1.0000x reference)
//
#include <hip/hip_runtime.h>

// BeliefUpdate: b_{t+1} = normalize((b_t+eps) * W), W = (lik+eps)(m0+eps)(m1+eps)
//   => b_t = normalize(b_0 * W^t)  (inner +eps dropped: ~2.6e-8 rel err/iter)
// R2 structure: persistent waves (2048 blocks x 4 waves = exactly-resident at
// 8 blocks/CU), each wave grid-strides over row pairs with NO per-step sync:
// chg maxima accumulate in registers across steps; one cross-lane reduce +
// 9 atomics per wave at kernel end. Row layout: 32-lane group per row,
// 8 elems/lane; row-sum = 4x DPP row_ror add + 1 ds_swizzle xor16.

typedef float f32x4 __attribute__((ext_vector_type(4)));

static constexpr int   kD      = 256;
static constexpr float kEps    = 1e-10f;
static constexpr float kThresh = 1e-4f;
static constexpr int   kIters  = 10;
static constexpr int   kSlots  = 64;
static constexpr int   kBlocks = 2048;   // 8 blocks/CU * 256 CUs

template<int CTRL>
__device__ __forceinline__ float dpp_add(float v) {
    int t = __builtin_amdgcn_update_dpp(0, __float_as_int(v), CTRL, 0xf, 0xf, true);
    return v + __int_as_float(t);
}
template<int CTRL>
__device__ __forceinline__ float dpp_max(float v) {
    int t = __builtin_amdgcn_update_dpp(0, __float_as_int(v), CTRL, 0xf, 0xf, true);
    return fmaxf(v, __int_as_float(t));
}
__device__ __forceinline__ float swz_xor16(float v) {
    return __int_as_float(__builtin_amdgcn_ds_swizzle(__float_as_int(v), 0x401F));
}

__global__ __launch_bounds__(256) void bu_init(unsigned* __restrict__ slots) {
    for (int i = threadIdx.x; i < (kIters - 1) * kSlots; i += 256) slots[i] = 0u;
}

__global__ __launch_bounds__(256, 8) void bu_main(
    const float* __restrict__ prior,
    const float* __restrict__ lik,
    const float* __restrict__ msg,
    float* __restrict__ belief,
    unsigned* __restrict__ slots,
    int B)
{
    const int tid  = threadIdx.x;
    const int wave = tid >> 6;
    const int lane = tid & 63;
    const int sub  = lane >> 5;          // which row of the wave's pair
    const int q    = lane & 31;          // position within 32-lane row group
    const int wid  = blockIdx.x * 4 + wave;   // 0..8191
    const int NW   = gridDim.x * 4;           // 8192
    const int nPairs = B >> 1;                // 65536
    const size_t msgStride = (size_t)B * kD;

    float chgAcc[kIters - 1];
    #pragma unroll
    for (int t = 0; t < kIters - 1; ++t) chgAcc[t] = 0.f;

    for (int p = wid; p < nPairs; p += NW) {
        const int row = p * 2 + sub;
        const size_t off = (size_t)row * kD + (size_t)q * 8;

        const f32x4* pb = (const f32x4*)(prior + off);
        const f32x4* pl = (const f32x4*)(lik + off);
        const f32x4* p0 = (const f32x4*)(msg + off);
        const f32x4* p1 = (const f32x4*)(msg + msgStride + off);

        f32x4 vb0 = pb[0], vb1 = pb[1];
        f32x4 vl0 = pl[0], vl1 = pl[1];
        f32x4 va0 = p0[0], va1 = p0[1];
        f32x4 vc0 = p1[0], vc1 = p1[1];

        float u[8], W[8], pv[8];
        #pragma unroll
        for (int k = 0; k < 4; ++k) {
            u[k]     = vb0[k];
            u[4 + k] = vb1[k];
            W[k]     = (vl0[k] + kEps) * (va0[k] + kEps) * (vc0[k] + kEps);
            W[4 + k] = (vl1[k] + kEps) * (va1[k] + kEps) * (vc1[k] + kEps);
            pv[k]     = u[k];
            pv[4 + k] = u[4 + k];
        }

        #pragma unroll
        for (int t = 0; t < kIters; ++t) {
            #pragma unroll
            for (int j = 0; j < 8; ++j) u[j] *= W[j];
            float s = ((u[0] + u[1]) + (u[2] + u[3])) + ((u[4] + u[5]) + (u[6] + u[7]));
            s = dpp_add<0x121>(s);   // row_ror:1
            s = dpp_add<0x122>(s);   // row_ror:2
            s = dpp_add<0x124>(s);   // row_ror:4
            s = dpp_add<0x128>(s);   // row_ror:8 -> 16-lane sum
            s += swz_xor16(s);       // -> 32-lane row sum
            const float inv = __builtin_amdgcn_rcpf(s);
            if (t < kIters - 1) {
                float c = 0.f;
                #pragma unroll
                for (int j = 0; j < 8; ++j) {
                    float nb = u[j] * inv;
                    c = fmaxf(c, fabsf(nb - pv[j]));
                    pv[j] = nb;
                }
                chgAcc[t] = fmaxf(chgAcc[t], c);
            } else {
                #pragma unroll
                for (int j = 0; j < 8; ++j) pv[j] = u[j] * inv;
            }
        }

        f32x4 o0 = {pv[0], pv[1], pv[2], pv[3]};
        f32x4 o1 = {pv[4], pv[5], pv[6], pv[7]};
        __builtin_nontemporal_store(o0, (f32x4*)(belief + off));
        __builtin_nontemporal_store(o1, (f32x4*)(belief + off) + 1);
    }

    // once per wave: reduce chgAcc across all 64 lanes, then 9 atomics
    #pragma unroll
    for (int t = 0; t < kIters - 1; ++t) {
        float v = chgAcc[t];
        v = dpp_max<0x121>(v);
        v = dpp_max<0x122>(v);
        v = dpp_max<0x124>(v);
        v = dpp_max<0x128>(v);
        v = fmaxf(v, swz_xor16(v));
        v = fmaxf(v, __shfl_xor(v, 32));
        chgAcc[t] = v;
    }
    if (lane == 0) {
        #pragma unroll
        for (int t = 0; t < kIters - 1; ++t)
            atomicMax(&slots[t * kSlots + (wid & (kSlots - 1))],
                      __float_as_uint(chgAcc[t]));
    }
}

__global__ __launch_bounds__(64) void bu_finalize(
    const unsigned* __restrict__ slots,
    float* __restrict__ iters_out,
    int* __restrict__ flag)
{
    const int lane = threadIdx.x & 63;
    float chg[kIters - 1];
    #pragma unroll
    for (int t = 0; t < kIters - 1; ++t) {
        float v = __uint_as_float(slots[t * kSlots + lane]);
        #pragma unroll
        for (int o = 32; o > 0; o >>= 1) v = fmaxf(v, __shfl_xor(v, o));
        chg[t] = v;
    }
    if (threadIdx.x == 0) {
        int iters = 0;
        bool done = false;
        #pragma unroll
        for (int t = 0; t < kIters; ++t) {
            if (!done) iters++;
            if (t < kIters - 1 && chg[t] < kThresh) done = true;
        }
        *iters_out = (float)iters;
        *flag = (iters < kIters) ? iters : -1;
    }
}

// Rare path: recompute b_k (eps-exact iteration) if converged before iter 10.
__global__ __launch_bounds__(256) void bu_phaseC(
    const float* __restrict__ prior,
    const float* __restrict__ lik,
    const float* __restrict__ msg,
    float* __restrict__ belief,
    const int* __restrict__ flag,
    int B)
{
    const int k = *flag;
    if (k < 0) return;
    const int wave = threadIdx.x >> 6;
    const int lane = threadIdx.x & 63;
    const int g    = lane >> 4;
    const int q    = lane & 15;
    const int nUnits = B / 16;
    for (int u2 = blockIdx.x; u2 < nUnits; u2 += gridDim.x) {
        const int row = (u2 * 4 + wave) * 4 + g;
        const size_t off = (size_t)row * kD + (size_t)q * 16;
        const float* p0 = prior + off;
        const float* p1 = lik   + off;
        const float* p2 = msg   + off;
        const float* p3 = msg   + (size_t)B * kD + off;
        float b[16], W[16];
        #pragma unroll
        for (int c = 0; c < 4; ++c) {
            float4 vb = *(const float4*)(p0 + 4 * c);
            float4 vl = *(const float4*)(p1 + 4 * c);
            float4 v0 = *(const float4*)(p2 + 4 * c);
            float4 v1 = *(const float4*)(p3 + 4 * c);
            b[4*c+0] = vb.x; b[4*c+1] = vb.y; b[4*c+2] = vb.z; b[4*c+3] = vb.w;
            W[4*c+0] = (vl.x + kEps) * (v0.x + kEps) * (v1.x + kEps);
            W[4*c+1] = (vl.y + kEps) * (v0.y + kEps) * (v1.y + kEps);
            W[4*c+2] = (vl.z + kEps) * (v0.z + kEps) * (v1.z + kEps);
            W[4*c+3] = (vl.w + kEps) * (v0.w + kEps) * (v1.w + kEps);
        }
        for (int t = 0; t < k; ++t) {
            float pp[16];
            float s = 0.f;
            #pragma unroll
            for (int j = 0; j < 16; ++j) { pp[j] = (b[j] + kEps) * W[j]; s += pp[j]; }
            s += __shfl_xor(s, 1);
            s += __shfl_xor(s, 2);
            s += __shfl_xor(s, 4);
            s += __shfl_xor(s, 8);
            const float inv = 1.0f / s;
            #pragma unroll
            for (int j = 0; j < 16; ++j) b[j] = pp[j] * inv;
        }
        float* po = belief + off;
        #pragma unroll
        for (int c = 0; c < 4; ++c)
            *(float4*)(po + 4 * c) = make_float4(b[4*c], b[4*c+1], b[4*c+2], b[4*c+3]);
    }
}

extern "C" void kernel_launch(void* const* d_in, const int* in_sizes, int n_in,
                              void* d_out, int out_size, void* d_ws, size_t ws_size,
                              hipStream_t stream) {
    const float* prior = (const float*)d_in[0];
    const float* lik   = (const float*)d_in[1];
    const float* msg   = (const float*)d_in[2];
    const int B = in_sizes[0] / kD;          // 131072

    float* belief    = (float*)d_out;
    float* iters_out = belief + (size_t)B * kD;

    int*      flag  = (int*)d_ws;
    unsigned* slots = (unsigned*)((char*)d_ws + 64);

    bu_init<<<1, 256, 0, stream>>>(slots);
    bu_main<<<kBlocks, 256, 0, stream>>>(prior, lik, msg, belief, slots, B);
    bu_finalize<<<1, 64, 0, stream>>>(slots, iters_out, flag);
    bu_phaseC<<<256, 256, 0, stream>>>(prior, lik, msg, belief, flag, B);
}